// Round 8
// baseline (383.853 us; speedup 1.0000x reference)
//
#include <hip/hip_runtime.h>
#include <hip/hip_bf16.h>
#include <stdint.h>

// Problem constants (fixed by reference)
#define B_  4
#define N_  8192
#define M_  8192
#define D_  64
#define NT_ 64    // N_/128
#define RBN ((B_ * N_) / 16)   // 2048 16-row blocks on A side
#define INF_BITS 0x7F800000    // +inf float bits; stored mins are squared dists (>=0 for this
                               // data), so signed-int atomicMin == float min (as all passing rounds)

typedef __attribute__((ext_vector_type(8))) short bhalf8;   // 8 bf16 (MFMA A/B frag)
typedef __attribute__((ext_vector_type(4))) float f32x4;    // MFMA C/D frag

// ---- workspace layout (bytes) ----  TOTAL 11,272,192 (~10.75 MB), inside proven envelope.
// A'/B': bf16, K=64 (2 k-steps of 32), fragment-chunk order as all rounds.
// nA/nB: exact fp32 ||row||^2 (row norms ride the MFMA C-operand; col norms added in epilogue).
// rowpart: plain disjoint per-mcp row partials (no atomics). colpart: 16 slots (nt&15) of
// col partials, fire-and-forget atomicMin at 4-way contention.
// NOTE: tile's 2-ahead pipeline over-reads Bp by up to 2 steps at the end (b=3, mcp=3):
// max byte = OFF_B + ~4,210,704 = 8,405,008 -> lands in the nA region, inside workspace.
static const size_t OFF_A  = 0;                                        // 4,194,304
static const size_t OFF_B  = (size_t)B_ * N_ * D_ * 2;                 // 4,194,304
static const size_t OFF_NA = OFF_B + (size_t)B_ * M_ * D_ * 2;         // 8,388,608
static const size_t OFF_NB = OFF_NA + (size_t)B_ * N_ * 4;             // 8,519,680
static const size_t OFF_RP = OFF_NB + (size_t)B_ * M_ * 4;             // 8,650,752  rowpart: 4 x 32768 f
static const size_t OFF_CP = OFF_RP + (size_t)4 * B_ * N_ * 4;         // 9,175,040  colpart: B_ x 16 x 8192 int
// end: OFF_CP + 2,097,152 = 11,272,192

__device__ __forceinline__ short bf16bits(float x) {
    union { __hip_bfloat16 h; unsigned short u; } cv;
    cv.h = __float2bfloat16(x);
    return (short)cv.u;
}
__device__ __forceinline__ float min3f(float a, float b, float c) {
    return fminf(fminf(a, b), c);   // -> v_min3_f32
}

// ---------------- prep: K=64 fragment layout + fp32 norms; init colpart + out ----------------
__global__ __launch_bounds__(256) void chamfer_prep(
        const float* __restrict__ f, const float* __restrict__ f2,
        unsigned short* __restrict__ Ap, unsigned short* __restrict__ Bp,
        float* __restrict__ nA, float* __restrict__ nB,
        int* __restrict__ colpart, float* __restrict__ out) {
    const int tid = threadIdx.x;
    const int gid = blockIdx.x * 256 + tid;          // 1024 blocks -> 262,144 threads
    if (gid == 0) out[0] = 0.f;                      // finalize atomicAdds into this
    colpart[gid] = INF_BITS;                         // 524,288 ints: 2 per thread
    colpart[gid + 262144] = INF_BITS;

    const int w = gid >> 6;                          // 16-row block id, 0..4095
    const int lane = tid & 63;
    const int q = lane >> 4, c = lane & 15;
    const bool isA = w < RBN;
    const int rb = isA ? w : w - RBN;
    const float* src = isA ? f : f2;
    unsigned short* dst = isA ? Ap : Bp;
    float* ndst = isA ? nA : nB;
    const float scale = isA ? -2.0f : 1.0f;          // fold the -2 into A; exact in bf16

    const float* row = src + ((size_t)rb * 16 + c) * 64;
    f32x4 u0 = *(const f32x4*)(row + q * 8);
    f32x4 u1 = *(const f32x4*)(row + q * 8 + 4);
    f32x4 u2 = *(const f32x4*)(row + 32 + q * 8);
    f32x4 u3 = *(const f32x4*)(row + 32 + q * 8 + 4);

    float ss = 0.f;
    #pragma unroll
    for (int k = 0; k < 4; k++)
        ss += u0[k] * u0[k] + u1[k] * u1[k] + u2[k] * u2[k] + u3[k] * u3[k];
    ss += __shfl_xor(ss, 16, 64);
    ss += __shfl_xor(ss, 32, 64);                    // full ||row c||^2 in every lane (fp32, exact)

    bhalf8 o0, o1;
    #pragma unroll
    for (int k = 0; k < 4; k++) {
        o0[k]     = bf16bits(u0[k] * scale);
        o0[4 + k] = bf16bits(u1[k] * scale);
        o1[k]     = bf16bits(u2[k] * scale);
        o1[4 + k] = bf16bits(u3[k] * scale);
    }
    if (q == 0) ndst[rb * 16 + c] = ss;              // 16 consecutive floats per wave
    *(bhalf8*)(dst + ((size_t)(rb * 2 + 0) * 64 + lane) * 8) = o0;
    *(bhalf8*)(dst + ((size_t)(rb * 2 + 1) * 64 + lane) * 8) = o1;
}

// ---------------- tile kernel: round-7 structure + VGPR cap (occupancy cliff fix) ----------------
// grid (mcp=4, nt=64, b=4) = 1024 blocks; wave tile 64 rows x 32 cols/step, 32 steps.
// Round 7 regressed 50.7->72us purely because VGPR hit 136 (>128 cliff: 4->2 waves/SIMD,
// occupancy 18->10%). __launch_bounds__(256, 4) pins 4 waves/SIMD -> VGPR cap 128; the loop
// fit in 120 VGPR in round 3, so the cap forces remat, not in-loop spills. Epilogue unroll
// reduced 8->2 to cut its live-value spike (the likely regalloc max).
__global__ __launch_bounds__(256, 4) void chamfer_tile(
        const unsigned short* __restrict__ Ap, const unsigned short* __restrict__ Bp,
        const float* __restrict__ nA, const float* __restrict__ nB,
        float* __restrict__ rowpart, int* __restrict__ colpart) {
    const int mcp = blockIdx.x;  // 0..3 : 2048-col chunk
    const int nt = blockIdx.y;   // 0..63
    const int b  = blockIdx.z;   // 0..3
    const int tid = threadIdx.x;
    const int wave = tid >> 6, lane = tid & 63;
    const int wr = wave >> 1, wc = wave & 1;
    const int q = lane >> 4, c = lane & 15;

    __shared__ float colstore[4096];  // 16 KB: [step 0..31][wave 0..3][c*2+jj], write-once
    __shared__ float nyb2[2048];      // 8 KB: all 2048 col norms (prologue-written)
    __shared__ int rowmin[128];

    // ---- prologue ----
    *(f32x4*)&nyb2[tid * 4] = *(const f32x4*)(nB + (size_t)b * 8192 + mcp * 2048 + tid * 4);
    *(f32x4*)&nyb2[1024 + tid * 4] =
        *(const f32x4*)(nB + (size_t)b * 8192 + mcp * 2048 + 1024 + tid * 4);
    if (tid < 128) rowmin[tid] = INF_BITS;

    const int rbA0 = b * 512 + nt * 8 + wr * 4;
    bhalf8 af[4][2];
    #pragma unroll
    for (int i = 0; i < 4; i++)
        #pragma unroll
        for (int ks = 0; ks < 2; ks++)
            af[i][ks] = *(const bhalf8*)(Ap + ((size_t)((rbA0 + i) * 2 + ks) * 64 + lane) * 8);

    f32x4 cnx[4];
    {
        const float* nrow = nA + (size_t)b * 8192 + nt * 128 + wr * 64 + q * 4;
        #pragma unroll
        for (int i = 0; i < 4; i++)
            cnx[i] = *(const f32x4*)(nrow + i * 16);
    }

    f32x4 rv[4];                 // running row-min, rows i*16+q*4+r
    #pragma unroll
    for (int i = 0; i < 4; i++) rv[i] = (f32x4){3.0e38f, 3.0e38f, 3.0e38f, 3.0e38f};

    __syncthreads();             // nyb2 + rowmin visible; the ONLY pre-epilogue barrier

    // step s (0..31): cols (s>>1)*128 + wc*64 + (s&1)*32 + jj*16 + c; rb stride 1024 shorts.
    const unsigned short* base = Bp + (size_t)(b * 512 + mcp * 128 + wc * 4) * 1024 + lane * 8;
    auto bptr = [&](int s) { return base + ((s >> 1) * 8192 + (s & 1) * 2048); };

    auto loadB = [&](const unsigned short* p, bhalf8 (&bf)[2][2]) {
        #pragma unroll
        for (int jj = 0; jj < 2; jj++)
            #pragma unroll
            for (int ks = 0; ks < 2; ks++)
                bf[jj][ks] = *(const bhalf8*)(p + jj * 1024 + ks * 512);
    };

    auto process = [&](int s, bhalf8 (&bf)[2][2]) {
        const int cb = (s >> 1) * 128 + wc * 64 + (s & 1) * 32 + c;
        const float ny0 = nyb2[cb];       // 4-way same-address broadcast, free
        const float ny1 = nyb2[cb + 16];

        f32x4 acc[4][2];
        #pragma unroll
        for (int i = 0; i < 4; i++)
            #pragma unroll
            for (int jj = 0; jj < 2; jj++)
                acc[i][jj] = __builtin_amdgcn_mfma_f32_16x16x32_bf16(af[i][0], bf[jj][0], cnx[i], 0, 0, 0);
        #pragma unroll
        for (int i = 0; i < 4; i++)
            #pragma unroll
            for (int jj = 0; jj < 2; jj++)
                acc[i][jj] = __builtin_amdgcn_mfma_f32_16x16x32_bf16(af[i][1], bf[jj][1], acc[i][jj], 0, 0, 0);

        // sv = full squared distance; row-min fused
        float sv[4][2][4];
        #pragma unroll
        for (int i = 0; i < 4; i++)
            #pragma unroll
            for (int r = 0; r < 4; r++) {
                sv[i][0][r] = acc[i][0][r] + ny0;
                sv[i][1][r] = acc[i][1][r] + ny1;
                rv[i][r] = min3f(sv[i][0][r], sv[i][1][r], rv[i][r]);
            }

        // col-min over this lane's 16 rows (min3 tree), then q-reduction (shfl_xor 16/32)
        float t[2];
        #pragma unroll
        for (int jj = 0; jj < 2; jj++) {
            float t0 = min3f(sv[0][jj][0], sv[0][jj][1], sv[0][jj][2]);
            float t1 = min3f(sv[0][jj][3], sv[1][jj][0], sv[1][jj][1]);
            float t2 = min3f(sv[1][jj][2], sv[1][jj][3], sv[2][jj][0]);
            float t3 = min3f(sv[2][jj][1], sv[2][jj][2], sv[2][jj][3]);
            float t4 = min3f(sv[3][jj][0], sv[3][jj][1], sv[3][jj][2]);
            float tt = fminf(min3f(t0, t1, t2), min3f(t3, t4, sv[3][jj][3]));
            tt = fminf(tt, __shfl_xor(tt, 16, 64));
            tt = fminf(tt, __shfl_xor(tt, 32, 64));   // full 64-row col-min in every lane
            t[jj] = tt;
        }
        if (lane < 16)   // 16 lanes x 8B contiguous -> conflict-free ds_write_b64
            *(float2*)&colstore[(s * 4 + wave) * 32 + c * 2] = make_float2(t[0], t[1]);
    };

    // ---- 4-buffer, distance-2 pipeline over 32 steps ----
    bhalf8 Bf0[2][2], Bf1[2][2], Bf2[2][2], Bf3[2][2];
    loadB(bptr(0), Bf0);
    loadB(bptr(1), Bf1);
    #pragma unroll 1
    for (int sp = 0; sp < 8; sp++) {     // steps 4sp .. 4sp+3
        const int s = sp * 4;
        loadB(bptr(s + 2), Bf2);  process(s,     Bf0);
        loadB(bptr(s + 3), Bf3);  process(s + 1, Bf1);
        loadB(bptr(s + 4), Bf0);  process(s + 2, Bf2);   // sp==7: over-read (in-workspace)
        loadB(bptr(s + 5), Bf1);  process(s + 3, Bf3);   // sp==7: over-read (in-workspace)
    }

    // ---- epilogue: LDS row-min combine; plain rowpart stores; 4-way-contention colpart ----
    #pragma unroll
    for (int i = 0; i < 4; i++)
        #pragma unroll
        for (int r = 0; r < 4; r++)
            atomicMin(&rowmin[wr * 64 + i * 16 + q * 4 + r], __float_as_int(rv[i][r]));
    __syncthreads();                     // rowmin + all colstore writes visible

    if (tid < 128)
        rowpart[(size_t)mcp * 32768 + ((size_t)b * 64 + nt) * 128 + tid] =
            __int_as_float(rowmin[tid]);

    // colpart slot = nt & 15: 4 contributor blocks per address, fire-and-forget atomicMin,
    // coalesced 2048 consecutive ints per block. unroll 2 keeps the live-value spike small.
    int* cp = colpart + ((size_t)(b * 16 + (nt & 15))) * 8192 + mcp * 2048;
    #pragma unroll 2
    for (int k = 0; k < 8; k++) {
        const int col = k * 256 + tid;   // 0..2047
        const int s  = (col >> 7) * 2 + ((col >> 5) & 1);
        const int wcx = (col >> 6) & 1, jf = (col >> 4) & 1, cx = col & 15;
        const float m = fminf(colstore[(s * 4 + wcx)     * 32 + cx * 2 + jf],    // wr=0 wave
                              colstore[(s * 4 + 2 + wcx) * 32 + cx * 2 + jf]);   // wr=1 wave
        atomicMin(&cp[col], __float_as_int(m));
    }
}

// ---------------- finalize: min-reduce partials (2.5 MB) -> scalar ----------------
__global__ __launch_bounds__(256) void chamfer_finalize(
        const float* __restrict__ rowpart, const int* __restrict__ colpart,
        float* __restrict__ out) {
    const int gid = blockIdx.x * 256 + threadIdx.x;   // 64 blocks -> 16384 threads
    float s = 0.f;
    #pragma unroll
    for (int k = 0; k < 2; k++) {
        const int p = gid + k * 16384;                // 0..32767
        // rows: min over 4 mcp partials
        float rm = fminf(fminf(rowpart[p], rowpart[32768 + p]),
                         fminf(rowpart[65536 + p], rowpart[98304 + p]));
        // cols: min over 16 slots (consecutive gid -> consecutive col: coalesced)
        const int bb = p >> 13, col = p & 8191;
        const int* cbase = colpart + (size_t)bb * 16 * 8192 + col;
        float cm = 3.0e38f;
        #pragma unroll
        for (int sl = 0; sl < 16; sl++)
            cm = fminf(cm, __int_as_float(cbase[(size_t)sl * 8192]));
        s += rm * (1.0f / 32768.f) + cm * (1.0f / 32768.f);   // 1/(B*N) == 1/(B*M)
    }
    __shared__ float sb[256];
    const int tid = threadIdx.x;
    sb[tid] = s;
    __syncthreads();
    for (int st = 128; st > 0; st >>= 1) {
        if (tid < st) sb[tid] += sb[tid + st];
        __syncthreads();
    }
    if (tid == 0) atomicAdd(out, sb[0]);
}

extern "C" void kernel_launch(void* const* d_in, const int* in_sizes, int n_in,
                              void* d_out, int out_size, void* d_ws, size_t ws_size,
                              hipStream_t stream) {
    const float* f  = (const float*)d_in[0];
    const float* f2 = (const float*)d_in[1];
    char* ws = (char*)d_ws;
    unsigned short* Ap = (unsigned short*)(ws + OFF_A);
    unsigned short* Bp = (unsigned short*)(ws + OFF_B);
    float* nA      = (float*)(ws + OFF_NA);
    float* nB      = (float*)(ws + OFF_NB);
    float* rowpart = (float*)(ws + OFF_RP);
    int*   colpart = (int*)(ws + OFF_CP);
    float* out     = (float*)d_out;

    // prep: K=64 fragment layout + fp32 norms; inits colpart/out
    chamfer_prep<<<dim3(1024), dim3(256), 0, stream>>>(f, f2, Ap, Bp, nA, nB, colpart, out);

    // main: 1024 blocks, 32-step barrier-free loop, distance-2 prefetch, VGPR<=128
    chamfer_tile<<<dim3(4, NT_, B_), dim3(256), 0, stream>>>(Ap, Bp, nA, nB, rowpart, colpart);

    // finalize: 2.5 MB partial-min reduce -> scalar
    chamfer_finalize<<<dim3(64), dim3(256), 0, stream>>>(rowpart, colpart, out);
}

// Round 9
// 113.596 us; speedup vs baseline: 3.3791x; 3.3791x over previous
//
#include <hip/hip_runtime.h>
#include <hip/hip_bf16.h>
#include <stdint.h>

// Problem constants (fixed by reference)
#define B_  4
#define N_  8192
#define M_  8192
#define D_  64
#define NT_ 64    // N_/128
#define RBN ((B_ * N_) / 16)   // 2048 16-row blocks on A side
#define INF_BITS 0x7F800000    // +inf float bits; stored mins are squared dists (>=0),
                               // so signed-int atomicMin == float min (as all passing rounds)

typedef __attribute__((ext_vector_type(8))) short bhalf8;   // 8 bf16 (MFMA A/B frag)
typedef __attribute__((ext_vector_type(4))) float f32x4;    // MFMA C/D frag

// ---- workspace layout (bytes) ----  TOTAL 11,272,192 (~10.75 MB), proven envelope (r7/r8).
// A'/B': bf16, K=64 (2 k-steps of 32), fragment-chunk order as all rounds.
// nA/nB: exact fp32 ||row||^2 (row norms ride the MFMA C-operand; col norms via LDS table).
// rowpart: plain disjoint per-mcp row partials (no atomics).
// colpart: 16 slots (nt&15) of col partials -> fire-and-forget atomicMin at 4-way contention
//   (this round's ONLY change vs round-4's 50.7us kernel: epilogue/flush targets; the
//   64-way lock-step colglob storm + 8-way rowglob storm are replaced at FIXED occupancy).
// NOTE: tile's 2-ahead pipeline over-reads Bp by up to 2 steps at the end (b=3, mcp=3):
// max byte = OFF_B + ~4,210,704 = 8,405,008 -> lands in the nA region, inside workspace.
static const size_t OFF_A  = 0;                                        // 4,194,304
static const size_t OFF_B  = (size_t)B_ * N_ * D_ * 2;                 // 4,194,304
static const size_t OFF_NA = OFF_B + (size_t)B_ * M_ * D_ * 2;         // 8,388,608
static const size_t OFF_NB = OFF_NA + (size_t)B_ * N_ * 4;             // 8,519,680
static const size_t OFF_RP = OFF_NB + (size_t)B_ * M_ * 4;             // 8,650,752  rowpart: 4 x 32768 f
static const size_t OFF_CP = OFF_RP + (size_t)4 * B_ * N_ * 4;         // 9,175,040  colpart: 4 x 16 x 8192 int
// end: OFF_CP + 2,097,152 = 11,272,192

__device__ __forceinline__ short bf16bits(float x) {
    union { __hip_bfloat16 h; unsigned short u; } cv;
    cv.h = __float2bfloat16(x);
    return (short)cv.u;
}
__device__ __forceinline__ float min3f(float a, float b, float c) {
    return fminf(fminf(a, b), c);   // -> v_min3_f32
}

// ---------------- prep: K=64 fragment layout + fp32 norms; init colpart + out ----------------
__global__ __launch_bounds__(256) void chamfer_prep(
        const float* __restrict__ f, const float* __restrict__ f2,
        unsigned short* __restrict__ Ap, unsigned short* __restrict__ Bp,
        float* __restrict__ nA, float* __restrict__ nB,
        int* __restrict__ colpart, float* __restrict__ out) {
    const int tid = threadIdx.x;
    const int gid = blockIdx.x * 256 + tid;          // 1024 blocks -> 262,144 threads
    if (gid == 0) out[0] = 0.f;                      // finalize atomicAdds into this
    colpart[gid] = INF_BITS;                         // 524,288 ints: 2 per thread
    colpart[gid + 262144] = INF_BITS;

    const int w = gid >> 6;                          // 16-row block id, 0..4095
    const int lane = tid & 63;
    const int q = lane >> 4, c = lane & 15;
    const bool isA = w < RBN;
    const int rb = isA ? w : w - RBN;
    const float* src = isA ? f : f2;
    unsigned short* dst = isA ? Ap : Bp;
    float* ndst = isA ? nA : nB;
    const float scale = isA ? -2.0f : 1.0f;          // fold the -2 into A; exact in bf16

    const float* row = src + ((size_t)rb * 16 + c) * 64;
    f32x4 u0 = *(const f32x4*)(row + q * 8);
    f32x4 u1 = *(const f32x4*)(row + q * 8 + 4);
    f32x4 u2 = *(const f32x4*)(row + 32 + q * 8);
    f32x4 u3 = *(const f32x4*)(row + 32 + q * 8 + 4);

    float ss = 0.f;
    #pragma unroll
    for (int k = 0; k < 4; k++)
        ss += u0[k] * u0[k] + u1[k] * u1[k] + u2[k] * u2[k] + u3[k] * u3[k];
    ss += __shfl_xor(ss, 16, 64);
    ss += __shfl_xor(ss, 32, 64);                    // full ||row c||^2 in every lane (fp32, exact)

    bhalf8 o0, o1;
    #pragma unroll
    for (int k = 0; k < 4; k++) {
        o0[k]     = bf16bits(u0[k] * scale);
        o0[4 + k] = bf16bits(u1[k] * scale);
        o1[k]     = bf16bits(u2[k] * scale);
        o1[4 + k] = bf16bits(u3[k] * scale);
    }
    if (q == 0) ndst[rb * 16 + c] = ss;              // 16 consecutive floats per wave
    *(bhalf8*)(dst + ((size_t)(rb * 2 + 0) * 64 + lane) * 8) = o0;
    *(bhalf8*)(dst + ((size_t)(rb * 2 + 1) * 64 + lane) * 8) = o1;
}

// ---------------- tile kernel: round-4 structure verbatim; low-contention flush targets ----------------
// grid (mcp=4, nt=64, b=4) = 1024 blocks; wave tile 64 rows x 32 cols/step, 32 steps;
// distance-2 register prefetch (4 named buffers); write-once colstore + 2 chunkflushes.
// NO launch_bounds occupancy arg (round-8 lesson: it forced VGPR=64 + full scratch spill).
__global__ __launch_bounds__(256) void chamfer_tile(
        const unsigned short* __restrict__ Ap, const unsigned short* __restrict__ Bp,
        const float* __restrict__ nA, const float* __restrict__ nB,
        float* __restrict__ rowpart, int* __restrict__ colpart) {
    const int mcp = blockIdx.x;  // 0..3 : 16-tile (2048-col) chunk-pair
    const int nt = blockIdx.y;   // 0..63
    const int b  = blockIdx.z;   // 0..3
    const int tid = threadIdx.x;
    const int wave = tid >> 6, lane = tid & 63;
    const int wr = wave >> 1, wc = wave & 1;
    const int q = lane >> 4, c = lane & 15;

    // colstore: per-(step-in-chunk, wave) region of 64 lanes x 2 jj floats. Written once
    // per chunk (plain b64 stores, lane-contiguous -> conflict-free), reduced at flush.
    __shared__ float colstore[8192];  // 64 regions x 128 floats = 32 KB
    __shared__ int rowmin[128];
    __shared__ float nyb[1024];       // current chunk's 1024 col norms (fp32)

    // stage chunk-0 col norms (4KB) + init rowmin
    *(f32x4*)&nyb[tid * 4] = *(const f32x4*)(nB + (size_t)b * 8192 + mcp * 2048 + tid * 4);
    if (tid < 128) rowmin[tid] = INF_BITS;
    __syncthreads();

    // A fragments: rows nt*128 + wr*64 + i*16 + c, 2 k-steps. Loaded once (coalesced 1KB).
    const int rbA0 = b * 512 + nt * 8 + wr * 4;
    bhalf8 af[4][2];
    #pragma unroll
    for (int i = 0; i < 4; i++)
        #pragma unroll
        for (int ks = 0; ks < 2; ks++)
            af[i][ks] = *(const bhalf8*)(Ap + ((size_t)((rbA0 + i) * 2 + ks) * 64 + lane) * 8);

    // C-init row norms: acc reg r of tile i is row i*16 + q*4 + r -> one f32x4 load per i
    f32x4 cnx[4];
    {
        const float* nrow = nA + (size_t)b * 8192 + nt * 128 + wr * 64 + q * 4;
        #pragma unroll
        for (int i = 0; i < 4; i++)
            cnx[i] = *(const f32x4*)(nrow + i * 16);
    }

    f32x4 rv[4];                 // running row-min over all 2048 cols, rows i*16+q*4+r
    #pragma unroll
    for (int i = 0; i < 4; i++) rv[i] = (f32x4){3.0e38f, 3.0e38f, 3.0e38f, 3.0e38f};

    // step s (0..31): chunk cc = s>>4, mtl = (s>>1)&7, half = s&1;
    // offset = (s>>1)*8192 + (s&1)*2048 shorts.
    const unsigned short* base = Bp + (size_t)(b * 512 + mcp * 128 + wc * 4) * 1024 + lane * 8;
    auto bptr = [&](int s) { return base + ((s >> 1) * 8192 + (s & 1) * 2048); };

    auto loadB = [&](const unsigned short* p, bhalf8 (&bf)[2][2]) {
        #pragma unroll
        for (int jj = 0; jj < 2; jj++)
            #pragma unroll
            for (int ks = 0; ks < 2; ks++)
                bf[jj][ks] = *(const bhalf8*)(p + jj * 1024 + ks * 512);
    };

    // stl = step-in-chunk 0..15 (mtl = stl>>1, half = stl&1)
    auto process = [&](int stl, bhalf8 (&bf)[2][2]) {
        const int cb = (stl >> 1) * 128 + wc * 64 + (stl & 1) * 32 + c;
        const float ny0 = nyb[cb];          // 4-way same-address broadcast, conflict-free
        const float ny1 = nyb[cb + 16];

        f32x4 acc[4][2];
        #pragma unroll
        for (int i = 0; i < 4; i++)
            #pragma unroll
            for (int jj = 0; jj < 2; jj++)
                acc[i][jj] = __builtin_amdgcn_mfma_f32_16x16x32_bf16(af[i][0], bf[jj][0], cnx[i], 0, 0, 0);
        #pragma unroll
        for (int i = 0; i < 4; i++)
            #pragma unroll
            for (int jj = 0; jj < 2; jj++)
                acc[i][jj] = __builtin_amdgcn_mfma_f32_16x16x32_bf16(af[i][1], bf[jj][1], acc[i][jj], 0, 0, 0);

        // sv = full squared distance; row-min fused as min3(sv0, sv1, rv)
        float sv[4][2][4];
        #pragma unroll
        for (int i = 0; i < 4; i++)
            #pragma unroll
            for (int r = 0; r < 4; r++) {
                sv[i][0][r] = acc[i][0][r] + ny0;
                sv[i][1][r] = acc[i][1][r] + ny1;
                rv[i][r] = min3f(sv[i][0][r], sv[i][1][r], rv[i][r]);
            }

        // col-min over this lane's 16 rows: balanced min3 tree, then ONE ds_write_b64
        float t[2];
        #pragma unroll
        for (int jj = 0; jj < 2; jj++) {
            float t0 = min3f(sv[0][jj][0], sv[0][jj][1], sv[0][jj][2]);
            float t1 = min3f(sv[0][jj][3], sv[1][jj][0], sv[1][jj][1]);
            float t2 = min3f(sv[1][jj][2], sv[1][jj][3], sv[2][jj][0]);
            float t3 = min3f(sv[2][jj][1], sv[2][jj][2], sv[2][jj][3]);
            float t4 = min3f(sv[3][jj][0], sv[3][jj][1], sv[3][jj][2]);
            t[jj] = fminf(min3f(t0, t1, t2), min3f(t3, t4, sv[3][jj][3]));
        }
        *(float2*)&colstore[((stl * 4 + wave) * 64 + lane) * 2] = make_float2(t[0], t[1]);
    };

    // flush one chunk's colstore -> colpart slot (nt&15): 4 contributor blocks per address
    // (vs 64 lock-step contributors to colglob in round 4 — the experiment's one variable).
    auto chunkflush = [&](int cc) {
        __syncthreads();                              // all colstore writes visible
        #pragma unroll
        for (int k = 0; k < 4; k++) {
            const int col = k * 256 + tid;            // 0..1023 in-chunk col
            const int mtl = col >> 7, rem = col & 127;
            const int wcx = (rem >> 6) & 1, hf = (rem >> 5) & 1;
            const int jf = (rem >> 4) & 1, cx = rem & 15;
            const int sl = mtl * 2 + hf;
            float m = __int_as_float(INF_BITS);
            #pragma unroll
            for (int wrx = 0; wrx < 2; wrx++) {       // 8 contributors: q x wr
                const int fb = (sl * 4 + wrx * 2 + wcx) * 128 + cx * 2 + jf;
                float m0 = fminf(colstore[fb], colstore[fb + 32]);
                float m1 = fminf(colstore[fb + 64], colstore[fb + 96]);
                m = fminf(m, fminf(m0, m1));
            }
            atomicMin(&colpart[((size_t)(b * 16 + (nt & 15))) * 8192 +
                               mcp * 2048 + cc * 1024 + col], __float_as_int(m));
        }
        if (cc == 0)
            *(f32x4*)&nyb[tid * 4] =
                *(const f32x4*)(nB + (size_t)b * 8192 + mcp * 2048 + 1024 + tid * 4);
        __syncthreads();                              // nyb ready; colstore reusable
    };

    // ---- 4-buffer, distance-2 pipeline over 32 steps (buffer names static; rule-#20 safe) ----
    bhalf8 Bf0[2][2], Bf1[2][2], Bf2[2][2], Bf3[2][2];
    loadB(bptr(0), Bf0);
    loadB(bptr(1), Bf1);
    #pragma unroll 1
    for (int sp = 0; sp < 8; sp++) {     // steps 4sp .. 4sp+3
        if (sp == 4) chunkflush(0);      // block-uniform; chunk-1 loads already in flight
        const int s = sp * 4;
        const int sl = s & 15;
        loadB(bptr(s + 2), Bf2);  process(sl,     Bf0);
        loadB(bptr(s + 3), Bf3);  process(sl + 1, Bf1);
        loadB(bptr(s + 4), Bf0);  process(sl + 2, Bf2);   // sp==7: over-read (in-workspace)
        loadB(bptr(s + 5), Bf1);  process(sl + 3, Bf3);   // sp==7: over-read (in-workspace)
    }
    chunkflush(1);

    // flush register row-mins to LDS, then PLAIN disjoint rowpart stores (no global atomics)
    #pragma unroll
    for (int i = 0; i < 4; i++)
        #pragma unroll
        for (int r = 0; r < 4; r++)
            atomicMin(&rowmin[wr * 64 + i * 16 + q * 4 + r], __float_as_int(rv[i][r]));
    __syncthreads();
    if (tid < 128)
        rowpart[(size_t)mcp * 32768 + ((size_t)b * 64 + nt) * 128 + tid] =
            __int_as_float(rowmin[tid]);
}

// ---------------- finalize: min-reduce partials (2.5 MB) -> scalar ----------------
__global__ __launch_bounds__(256) void chamfer_finalize(
        const float* __restrict__ rowpart, const int* __restrict__ colpart,
        float* __restrict__ out) {
    const int gid = blockIdx.x * 256 + threadIdx.x;   // 64 blocks -> 16384 threads
    float s = 0.f;
    #pragma unroll
    for (int k = 0; k < 2; k++) {
        const int p = gid + k * 16384;                // 0..32767
        // rows: min over 4 mcp partials
        float rm = fminf(fminf(rowpart[p], rowpart[32768 + p]),
                         fminf(rowpart[65536 + p], rowpart[98304 + p]));
        // cols: min over 16 slots (consecutive gid -> consecutive col: coalesced)
        const int bb = p >> 13, col = p & 8191;
        const int* cbase = colpart + (size_t)bb * 16 * 8192 + col;
        float cm = 3.0e38f;
        #pragma unroll
        for (int sl = 0; sl < 16; sl++)
            cm = fminf(cm, __int_as_float(cbase[(size_t)sl * 8192]));
        s += rm * (1.0f / 32768.f) + cm * (1.0f / 32768.f);   // 1/(B*N) == 1/(B*M)
    }
    __shared__ float sb[256];
    const int tid = threadIdx.x;
    sb[tid] = s;
    __syncthreads();
    for (int st = 128; st > 0; st >>= 1) {
        if (tid < st) sb[tid] += sb[tid + st];
        __syncthreads();
    }
    if (tid == 0) atomicAdd(out, sb[0]);
}

extern "C" void kernel_launch(void* const* d_in, const int* in_sizes, int n_in,
                              void* d_out, int out_size, void* d_ws, size_t ws_size,
                              hipStream_t stream) {
    const float* f  = (const float*)d_in[0];
    const float* f2 = (const float*)d_in[1];
    char* ws = (char*)d_ws;
    unsigned short* Ap = (unsigned short*)(ws + OFF_A);
    unsigned short* Bp = (unsigned short*)(ws + OFF_B);
    float* nA      = (float*)(ws + OFF_NA);
    float* nB      = (float*)(ws + OFF_NB);
    float* rowpart = (float*)(ws + OFF_RP);
    int*   colpart = (int*)(ws + OFF_CP);
    float* out     = (float*)d_out;

    // prep: K=64 fragment layout + fp32 norms; inits colpart/out
    chamfer_prep<<<dim3(1024), dim3(256), 0, stream>>>(f, f2, Ap, Bp, nA, nB, colpart, out);

    // main: 1024 blocks, round-4 loop, low-contention flush targets
    chamfer_tile<<<dim3(4, NT_, B_), dim3(256), 0, stream>>>(Ap, Bp, nA, nB, rowpart, colpart);

    // finalize: 2.5 MB partial-min reduce -> scalar
    chamfer_finalize<<<dim3(64), dim3(256), 0, stream>>>(rowpart, colpart, out);
}

// Round 10
// 112.572 us; speedup vs baseline: 3.4098x; 1.0091x over previous
//
#include <hip/hip_runtime.h>
#include <hip/hip_bf16.h>
#include <stdint.h>

// Problem constants (fixed by reference)
#define B_  4
#define N_  8192
#define M_  8192
#define D_  64
#define NT_ 64    // N_/128
#define RBN ((B_ * N_) / 16)   // 2048 16-row blocks on A side
#define INF_BITS 0x7F800000    // +inf float bits; stored mins are squared dists (>=0),
                               // so signed-int atomicMin == float min (as all passing rounds)

typedef __attribute__((ext_vector_type(8))) short bhalf8;   // 8 bf16 (MFMA A/B frag)
typedef __attribute__((ext_vector_type(4))) float f32x4;    // MFMA C/D frag

// ---- workspace layout (bytes) ----  TOTAL 11,272,192 (~10.75 MB), proven envelope (r7/r9).
// A'/B': bf16, K=64 (2 k-steps of 32), fragment-chunk order as all rounds.
// nA/nB: exact fp32 ||row||^2 (row norms ride the MFMA C-operand; col norms via LDS table).
// rowpart: plain disjoint per-mcp row partials (no atomics).
// colpart: 16 slots (nt&15) of col partials, fire-and-forget atomicMin at 4-way contention.
// THIS ROUND vs round 9 (113.6 total / 50.4 tile): ONE change — s_setprio(1) around each
// process's MFMA cluster (T5). The 4 waves/SIMD are from 4 INDEPENDENT blocks (role
// diversity), MfmaUtil 27% + trueVALU ~24% with a ~45% overlap gap: arbiter-limited regime.
// NOTE: tile's 2-ahead pipeline over-reads Bp by up to 2 steps at the end (b=3, mcp=3):
// max byte = OFF_B + ~4,210,704 = 8,405,008 -> lands in the nA region, inside workspace.
static const size_t OFF_A  = 0;                                        // 4,194,304
static const size_t OFF_B  = (size_t)B_ * N_ * D_ * 2;                 // 4,194,304
static const size_t OFF_NA = OFF_B + (size_t)B_ * M_ * D_ * 2;         // 8,388,608
static const size_t OFF_NB = OFF_NA + (size_t)B_ * N_ * 4;             // 8,519,680
static const size_t OFF_RP = OFF_NB + (size_t)B_ * M_ * 4;             // 8,650,752  rowpart: 4 x 32768 f
static const size_t OFF_CP = OFF_RP + (size_t)4 * B_ * N_ * 4;         // 9,175,040  colpart: 4 x 16 x 8192 int
// end: OFF_CP + 2,097,152 = 11,272,192

__device__ __forceinline__ short bf16bits(float x) {
    union { __hip_bfloat16 h; unsigned short u; } cv;
    cv.h = __float2bfloat16(x);
    return (short)cv.u;
}
__device__ __forceinline__ float min3f(float a, float b, float c) {
    return fminf(fminf(a, b), c);   // -> v_min3_f32
}

// ---------------- prep: K=64 fragment layout + fp32 norms; init colpart + out ----------------
__global__ __launch_bounds__(256) void chamfer_prep(
        const float* __restrict__ f, const float* __restrict__ f2,
        unsigned short* __restrict__ Ap, unsigned short* __restrict__ Bp,
        float* __restrict__ nA, float* __restrict__ nB,
        int* __restrict__ colpart, float* __restrict__ out) {
    const int tid = threadIdx.x;
    const int gid = blockIdx.x * 256 + tid;          // 1024 blocks -> 262,144 threads
    if (gid == 0) out[0] = 0.f;                      // finalize atomicAdds into this
    colpart[gid] = INF_BITS;                         // 524,288 ints: 2 per thread
    colpart[gid + 262144] = INF_BITS;

    const int w = gid >> 6;                          // 16-row block id, 0..4095
    const int lane = tid & 63;
    const int q = lane >> 4, c = lane & 15;
    const bool isA = w < RBN;
    const int rb = isA ? w : w - RBN;
    const float* src = isA ? f : f2;
    unsigned short* dst = isA ? Ap : Bp;
    float* ndst = isA ? nA : nB;
    const float scale = isA ? -2.0f : 1.0f;          // fold the -2 into A; exact in bf16

    const float* row = src + ((size_t)rb * 16 + c) * 64;
    f32x4 u0 = *(const f32x4*)(row + q * 8);
    f32x4 u1 = *(const f32x4*)(row + q * 8 + 4);
    f32x4 u2 = *(const f32x4*)(row + 32 + q * 8);
    f32x4 u3 = *(const f32x4*)(row + 32 + q * 8 + 4);

    float ss = 0.f;
    #pragma unroll
    for (int k = 0; k < 4; k++)
        ss += u0[k] * u0[k] + u1[k] * u1[k] + u2[k] * u2[k] + u3[k] * u3[k];
    ss += __shfl_xor(ss, 16, 64);
    ss += __shfl_xor(ss, 32, 64);                    // full ||row c||^2 in every lane (fp32, exact)

    bhalf8 o0, o1;
    #pragma unroll
    for (int k = 0; k < 4; k++) {
        o0[k]     = bf16bits(u0[k] * scale);
        o0[4 + k] = bf16bits(u1[k] * scale);
        o1[k]     = bf16bits(u2[k] * scale);
        o1[4 + k] = bf16bits(u3[k] * scale);
    }
    if (q == 0) ndst[rb * 16 + c] = ss;              // 16 consecutive floats per wave
    *(bhalf8*)(dst + ((size_t)(rb * 2 + 0) * 64 + lane) * 8) = o0;
    *(bhalf8*)(dst + ((size_t)(rb * 2 + 1) * 64 + lane) * 8) = o1;
}

// ---------------- tile kernel: round-9 structure + setprio(1) on MFMA clusters (T5) ----------------
// grid (mcp=4, nt=64, b=4) = 1024 blocks; wave tile 64 rows x 32 cols/step, 32 steps;
// distance-2 register prefetch (4 named buffers); write-once colstore + 2 chunkflushes.
// NO launch_bounds occupancy arg (round-8 lesson: it forced VGPR=64 + full scratch spill).
__global__ __launch_bounds__(256) void chamfer_tile(
        const unsigned short* __restrict__ Ap, const unsigned short* __restrict__ Bp,
        const float* __restrict__ nA, const float* __restrict__ nB,
        float* __restrict__ rowpart, int* __restrict__ colpart) {
    const int mcp = blockIdx.x;  // 0..3 : 16-tile (2048-col) chunk-pair
    const int nt = blockIdx.y;   // 0..63
    const int b  = blockIdx.z;   // 0..3
    const int tid = threadIdx.x;
    const int wave = tid >> 6, lane = tid & 63;
    const int wr = wave >> 1, wc = wave & 1;
    const int q = lane >> 4, c = lane & 15;

    // colstore: per-(step-in-chunk, wave) region of 64 lanes x 2 jj floats. Written once
    // per chunk (plain b64 stores, lane-contiguous -> conflict-free), reduced at flush.
    __shared__ float colstore[8192];  // 64 regions x 128 floats = 32 KB
    __shared__ int rowmin[128];
    __shared__ float nyb[1024];       // current chunk's 1024 col norms (fp32)

    // stage chunk-0 col norms (4KB) + init rowmin
    *(f32x4*)&nyb[tid * 4] = *(const f32x4*)(nB + (size_t)b * 8192 + mcp * 2048 + tid * 4);
    if (tid < 128) rowmin[tid] = INF_BITS;
    __syncthreads();

    // A fragments: rows nt*128 + wr*64 + i*16 + c, 2 k-steps. Loaded once (coalesced 1KB).
    const int rbA0 = b * 512 + nt * 8 + wr * 4;
    bhalf8 af[4][2];
    #pragma unroll
    for (int i = 0; i < 4; i++)
        #pragma unroll
        for (int ks = 0; ks < 2; ks++)
            af[i][ks] = *(const bhalf8*)(Ap + ((size_t)((rbA0 + i) * 2 + ks) * 64 + lane) * 8);

    // C-init row norms: acc reg r of tile i is row i*16 + q*4 + r -> one f32x4 load per i
    f32x4 cnx[4];
    {
        const float* nrow = nA + (size_t)b * 8192 + nt * 128 + wr * 64 + q * 4;
        #pragma unroll
        for (int i = 0; i < 4; i++)
            cnx[i] = *(const f32x4*)(nrow + i * 16);
    }

    f32x4 rv[4];                 // running row-min over all 2048 cols, rows i*16+q*4+r
    #pragma unroll
    for (int i = 0; i < 4; i++) rv[i] = (f32x4){3.0e38f, 3.0e38f, 3.0e38f, 3.0e38f};

    // step s (0..31): chunk cc = s>>4, mtl = (s>>1)&7, half = s&1;
    // offset = (s>>1)*8192 + (s&1)*2048 shorts.
    const unsigned short* base = Bp + (size_t)(b * 512 + mcp * 128 + wc * 4) * 1024 + lane * 8;
    auto bptr = [&](int s) { return base + ((s >> 1) * 8192 + (s & 1) * 2048); };

    auto loadB = [&](const unsigned short* p, bhalf8 (&bf)[2][2]) {
        #pragma unroll
        for (int jj = 0; jj < 2; jj++)
            #pragma unroll
            for (int ks = 0; ks < 2; ks++)
                bf[jj][ks] = *(const bhalf8*)(p + jj * 1024 + ks * 512);
    };

    // stl = step-in-chunk 0..15 (mtl = stl>>1, half = stl&1)
    auto process = [&](int stl, bhalf8 (&bf)[2][2]) {
        const int cb = (stl >> 1) * 128 + wc * 64 + (stl & 1) * 32 + c;
        const float ny0 = nyb[cb];          // 4-way same-address broadcast, conflict-free
        const float ny1 = nyb[cb + 16];

        // T5: boost wave priority while feeding the matrix pipe; drop for the VALU epilogue.
        f32x4 acc[4][2];
        __builtin_amdgcn_s_setprio(1);
        #pragma unroll
        for (int i = 0; i < 4; i++)
            #pragma unroll
            for (int jj = 0; jj < 2; jj++)
                acc[i][jj] = __builtin_amdgcn_mfma_f32_16x16x32_bf16(af[i][0], bf[jj][0], cnx[i], 0, 0, 0);
        #pragma unroll
        for (int i = 0; i < 4; i++)
            #pragma unroll
            for (int jj = 0; jj < 2; jj++)
                acc[i][jj] = __builtin_amdgcn_mfma_f32_16x16x32_bf16(af[i][1], bf[jj][1], acc[i][jj], 0, 0, 0);
        __builtin_amdgcn_s_setprio(0);

        // sv = full squared distance; row-min fused as min3(sv0, sv1, rv)
        float sv[4][2][4];
        #pragma unroll
        for (int i = 0; i < 4; i++)
            #pragma unroll
            for (int r = 0; r < 4; r++) {
                sv[i][0][r] = acc[i][0][r] + ny0;
                sv[i][1][r] = acc[i][1][r] + ny1;
                rv[i][r] = min3f(sv[i][0][r], sv[i][1][r], rv[i][r]);
            }

        // col-min over this lane's 16 rows: balanced min3 tree, then ONE ds_write_b64
        float t[2];
        #pragma unroll
        for (int jj = 0; jj < 2; jj++) {
            float t0 = min3f(sv[0][jj][0], sv[0][jj][1], sv[0][jj][2]);
            float t1 = min3f(sv[0][jj][3], sv[1][jj][0], sv[1][jj][1]);
            float t2 = min3f(sv[1][jj][2], sv[1][jj][3], sv[2][jj][0]);
            float t3 = min3f(sv[2][jj][1], sv[2][jj][2], sv[2][jj][3]);
            float t4 = min3f(sv[3][jj][0], sv[3][jj][1], sv[3][jj][2]);
            t[jj] = fminf(min3f(t0, t1, t2), min3f(t3, t4, sv[3][jj][3]));
        }
        *(float2*)&colstore[((stl * 4 + wave) * 64 + lane) * 2] = make_float2(t[0], t[1]);
    };

    // flush one chunk's colstore -> colpart slot (nt&15): 4 contributor blocks per address,
    // fire-and-forget atomicMin.
    auto chunkflush = [&](int cc) {
        __syncthreads();                              // all colstore writes visible
        #pragma unroll
        for (int k = 0; k < 4; k++) {
            const int col = k * 256 + tid;            // 0..1023 in-chunk col
            const int mtl = col >> 7, rem = col & 127;
            const int wcx = (rem >> 6) & 1, hf = (rem >> 5) & 1;
            const int jf = (rem >> 4) & 1, cx = rem & 15;
            const int sl = mtl * 2 + hf;
            float m = __int_as_float(INF_BITS);
            #pragma unroll
            for (int wrx = 0; wrx < 2; wrx++) {       // 8 contributors: q x wr
                const int fb = (sl * 4 + wrx * 2 + wcx) * 128 + cx * 2 + jf;
                float m0 = fminf(colstore[fb], colstore[fb + 32]);
                float m1 = fminf(colstore[fb + 64], colstore[fb + 96]);
                m = fminf(m, fminf(m0, m1));
            }
            atomicMin(&colpart[((size_t)(b * 16 + (nt & 15))) * 8192 +
                               mcp * 2048 + cc * 1024 + col], __float_as_int(m));
        }
        if (cc == 0)
            *(f32x4*)&nyb[tid * 4] =
                *(const f32x4*)(nB + (size_t)b * 8192 + mcp * 2048 + 1024 + tid * 4);
        __syncthreads();                              // nyb ready; colstore reusable
    };

    // ---- 4-buffer, distance-2 pipeline over 32 steps (buffer names static; rule-#20 safe) ----
    bhalf8 Bf0[2][2], Bf1[2][2], Bf2[2][2], Bf3[2][2];
    loadB(bptr(0), Bf0);
    loadB(bptr(1), Bf1);
    #pragma unroll 1
    for (int sp = 0; sp < 8; sp++) {     // steps 4sp .. 4sp+3
        if (sp == 4) chunkflush(0);      // block-uniform; chunk-1 loads already in flight
        const int s = sp * 4;
        const int sl = s & 15;
        loadB(bptr(s + 2), Bf2);  process(sl,     Bf0);
        loadB(bptr(s + 3), Bf3);  process(sl + 1, Bf1);
        loadB(bptr(s + 4), Bf0);  process(sl + 2, Bf2);   // sp==7: over-read (in-workspace)
        loadB(bptr(s + 5), Bf1);  process(sl + 3, Bf3);   // sp==7: over-read (in-workspace)
    }
    chunkflush(1);

    // flush register row-mins to LDS, then PLAIN disjoint rowpart stores (no global atomics)
    #pragma unroll
    for (int i = 0; i < 4; i++)
        #pragma unroll
        for (int r = 0; r < 4; r++)
            atomicMin(&rowmin[wr * 64 + i * 16 + q * 4 + r], __float_as_int(rv[i][r]));
    __syncthreads();
    if (tid < 128)
        rowpart[(size_t)mcp * 32768 + ((size_t)b * 64 + nt) * 128 + tid] =
            __int_as_float(rowmin[tid]);
}

// ---------------- finalize: min-reduce partials (2.5 MB) -> scalar ----------------
__global__ __launch_bounds__(256) void chamfer_finalize(
        const float* __restrict__ rowpart, const int* __restrict__ colpart,
        float* __restrict__ out) {
    const int gid = blockIdx.x * 256 + threadIdx.x;   // 64 blocks -> 16384 threads
    float s = 0.f;
    #pragma unroll
    for (int k = 0; k < 2; k++) {
        const int p = gid + k * 16384;                // 0..32767
        // rows: min over 4 mcp partials
        float rm = fminf(fminf(rowpart[p], rowpart[32768 + p]),
                         fminf(rowpart[65536 + p], rowpart[98304 + p]));
        // cols: min over 16 slots (consecutive gid -> consecutive col: coalesced)
        const int bb = p >> 13, col = p & 8191;
        const int* cbase = colpart + (size_t)bb * 16 * 8192 + col;
        float cm = 3.0e38f;
        #pragma unroll
        for (int sl = 0; sl < 16; sl++)
            cm = fminf(cm, __int_as_float(cbase[(size_t)sl * 8192]));
        s += rm * (1.0f / 32768.f) + cm * (1.0f / 32768.f);   // 1/(B*N) == 1/(B*M)
    }
    __shared__ float sb[256];
    const int tid = threadIdx.x;
    sb[tid] = s;
    __syncthreads();
    for (int st = 128; st > 0; st >>= 1) {
        if (tid < st) sb[tid] += sb[tid + st];
        __syncthreads();
    }
    if (tid == 0) atomicAdd(out, sb[0]);
}

extern "C" void kernel_launch(void* const* d_in, const int* in_sizes, int n_in,
                              void* d_out, int out_size, void* d_ws, size_t ws_size,
                              hipStream_t stream) {
    const float* f  = (const float*)d_in[0];
    const float* f2 = (const float*)d_in[1];
    char* ws = (char*)d_ws;
    unsigned short* Ap = (unsigned short*)(ws + OFF_A);
    unsigned short* Bp = (unsigned short*)(ws + OFF_B);
    float* nA      = (float*)(ws + OFF_NA);
    float* nB      = (float*)(ws + OFF_NB);
    float* rowpart = (float*)(ws + OFF_RP);
    int*   colpart = (int*)(ws + OFF_CP);
    float* out     = (float*)d_out;

    // prep: K=64 fragment layout + fp32 norms; inits colpart/out
    chamfer_prep<<<dim3(1024), dim3(256), 0, stream>>>(f, f2, Ap, Bp, nA, nB, colpart, out);

    // main: 1024 blocks, round-9 loop + T5 setprio on MFMA clusters
    chamfer_tile<<<dim3(4, NT_, B_), dim3(256), 0, stream>>>(Ap, Bp, nA, nB, rowpart, colpart);

    // finalize: 2.5 MB partial-min reduce -> scalar
    chamfer_finalize<<<dim3(64), dim3(256), 0, stream>>>(rowpart, colpart, out);
}